// Round 3
// baseline (350.976 us; speedup 1.0000x reference)
//
#include <hip/hip_runtime.h>
#include <hip/hip_bf16.h>
#include <stdint.h>

typedef __bf16 bf16_t;
typedef bf16_t bf16x8 __attribute__((ext_vector_type(8)));
typedef float f32x4 __attribute__((ext_vector_type(4)));

#define IN_F 4096
#define OUT_F 4096
#define M_ROWS 8192
#define RANK 16

// ---------------------------------------------------------------------------
// Kernel 1: dequantize 4-bit -> fp32, fold LoRA (Wp = W + B*A), store bf16.
// ---------------------------------------------------------------------------
__global__ __launch_bounds__(256)
void dequant_lora_kernel(const int* __restrict__ qw, const float* __restrict__ wmax,
                         const float* __restrict__ lA, const float* __restrict__ lB,
                         bf16_t* __restrict__ Wp) {
  const int tid = blockIdx.x * 256 + threadIdx.x;
  const int f0 = tid * 8;
  const int o  = f0 >> 12;
  const int i0 = f0 & (IN_F - 1);
  const int4 q4 = *(const int4*)(qw + (f0 >> 1));
  const float scale = wmax[f0 >> 6];
  const float st = scale * (2.0f / 15.0f);

  float v[8];
  {
    const int q0 = q4.x, q1 = q4.y, q2 = q4.z, q3 = q4.w;
    v[0] = (float)(q0 & 15)        * st - scale;
    v[1] = (float)((q0 >> 4) & 15) * st - scale;
    v[2] = (float)(q1 & 15)        * st - scale;
    v[3] = (float)((q1 >> 4) & 15) * st - scale;
    v[4] = (float)(q2 & 15)        * st - scale;
    v[5] = (float)((q2 >> 4) & 15) * st - scale;
    v[6] = (float)(q3 & 15)        * st - scale;
    v[7] = (float)((q3 >> 4) & 15) * st - scale;
  }

  const float* Brow = lB + o * RANK;
#pragma unroll
  for (int r = 0; r < RANK; ++r) {
    const float br = Brow[r];
    const float4 a0 = *(const float4*)(lA + r * IN_F + i0);
    const float4 a1 = *(const float4*)(lA + r * IN_F + i0 + 4);
    v[0] += br * a0.x; v[1] += br * a0.y; v[2] += br * a0.z; v[3] += br * a0.w;
    v[4] += br * a1.x; v[5] += br * a1.y; v[6] += br * a1.z; v[7] += br * a1.w;
  }

  bf16x8 ov;
#pragma unroll
  for (int j = 0; j < 8; ++j) ov[j] = (bf16_t)v[j];
  *(bf16x8*)(Wp + (size_t)f0) = ov;
}

// ---------------------------------------------------------------------------
// Kernel 2: x fp32 -> bf16 (vectorized)
// ---------------------------------------------------------------------------
__global__ __launch_bounds__(256)
void f32_to_bf16_kernel(const float* __restrict__ x, bf16_t* __restrict__ xb) {
  const size_t tid = (size_t)blockIdx.x * 256 + threadIdx.x;
  const float4 a0 = *(const float4*)(x + tid * 8);
  const float4 a1 = *(const float4*)(x + tid * 8 + 4);
  bf16x8 o;
  o[0] = (bf16_t)a0.x; o[1] = (bf16_t)a0.y; o[2] = (bf16_t)a0.z; o[3] = (bf16_t)a0.w;
  o[4] = (bf16_t)a1.x; o[5] = (bf16_t)a1.y; o[6] = (bf16_t)a1.z; o[7] = (bf16_t)a1.w;
  *(bf16x8*)(xb + tid * 8) = o;
}

// ---------------------------------------------------------------------------
// Kernel 3: 256x256 8-phase GEMM, deep pipeline (6-phase landing windows).
// A tile stored as 4 quadrant-blocks: quad q = rows {32q..32q+31} u
// {128+32q..+31} (the rows phase q reads), contiguous 8KB = 1 gload.
// A staged 2 tiles ahead, one quad/phase; B 2 tiles ahead in halves.
// Counted tails: ph0 vm(10), ph1 vm(12), ph2 vm(14), ph3 vm(10).
// ---------------------------------------------------------------------------
__device__ __forceinline__ void gld(const bf16_t* src, char* dst) {
  __builtin_amdgcn_global_load_lds((const __attribute__((address_space(1))) void*)src,
                                   (__attribute__((address_space(3))) void*)dst, 16, 0, 0);
}

#define BARRIER() __builtin_amdgcn_s_barrier()
#define WAIT_LGKM0() do { asm volatile("s_waitcnt lgkmcnt(0)" ::: "memory"); \
                          __builtin_amdgcn_sched_barrier(0); } while (0)
#define WAIT_VM(n) asm volatile("s_waitcnt vmcnt(" #n ")" ::: "memory")

// A quad stage: one 8KB gload; source rows 32q + (lr<32?lr:96+lr), swizzled col
#define STAGE_AQ(kt, buf, q) \
  gld(AsrcQ + (size_t)(q) * 32 * IN_F + (size_t)(kt) * 64, \
      ldsA + (buf) * 32768 + (q) * 8192 + tid * 16)
// B half stage: two 8KB gloads (64-row groups g = 2h, 2h+1)
#define STAGE_BH(kt, buf, h) do { \
  gld(Bsrc + (size_t)((h)*2)   * 64 * IN_F + (size_t)(kt) * 64, \
      ldsB + (buf) * 32768 + ((h)*2)   * 8192 + tid * 16); \
  gld(Bsrc + (size_t)((h)*2+1) * 64 * IN_F + (size_t)(kt) * 64, \
      ldsB + (buf) * 32768 + ((h)*2+1) * 8192 + tid * 16); \
} while (0)

#define LDA(buf, q, mm, cb) \
  (*(const bf16x8*)(ldsA + (buf)*32768 + (q)*8192 + aRowB + (mm)*2048 + (cb)))
#define LDB(buf, n, cb) \
  (*(const bf16x8*)(ldsB + (buf)*32768 + bRowB + (n)*2048 + (cb)))

#define PH(Q, CUR, RDB, STG, TW) do { \
  a[0][0] = LDA(CUR, Q, 0, cA0); a[0][1] = LDA(CUR, Q, 0, cA1); \
  a[1][0] = LDA(CUR, Q, 1, cA0); a[1][1] = LDA(CUR, Q, 1, cA1); \
  if (RDB) { \
    _Pragma("unroll") for (int n = 0; n < 4; ++n) { \
      b[n][0] = LDB(CUR, n, cA0); b[n][1] = LDB(CUR, n, cA1); } \
  } \
  STG; \
  BARRIER(); \
  WAIT_LGKM0(); \
  __builtin_amdgcn_s_setprio(1); \
  _Pragma("unroll") for (int kh = 0; kh < 2; ++kh) \
    _Pragma("unroll") for (int mm = 0; mm < 2; ++mm) \
      _Pragma("unroll") for (int n = 0; n < 4; ++n) \
        acc[2*(Q)+mm][n] = __builtin_amdgcn_mfma_f32_16x16x32_bf16( \
            a[mm][kh], b[n][kh], acc[2*(Q)+mm][n], 0, 0, 0); \
  __builtin_amdgcn_s_setprio(0); \
  TW; \
  BARRIER(); \
} while (0)

__global__ __launch_bounds__(512, 2)
void gemm_8phase_kernel(const bf16_t* __restrict__ Xb, const bf16_t* __restrict__ Wp,
                        const float* __restrict__ bias, float* __restrict__ C) {
  __shared__ __align__(16) bf16_t As[2 * 16384];   // 64 KiB: [2buf][4quad][64r][64c]
  __shared__ __align__(16) bf16_t Bs[2 * 16384];   // 64 KiB: [2buf][4grp][64r][64c]
  char* ldsA = (char*)As;
  char* ldsB = (char*)Bs;

  const int tid  = threadIdx.x;
  const int lane = tid & 63;
  const int wave = tid >> 6;
  const int wr = wave >> 2;           // 0..1 -> M half
  const int wc = wave & 3;            // 0..3 -> N quarter
  const int r16 = lane & 15;
  const int kg  = lane >> 4;          // 0..3

  const int bid = blockIdx.x;
  const int bm = bid >> 4;            // 0..31
  const int bn = bid & 15;            // 0..15

  // staging per-thread: local row lr in the 64-row staged block, swizzled col
  const int lr = tid >> 3;                          // 0..63
  const int sc = ((tid & 7) ^ (lr & 7)) << 3;       // element col (swizzled)
  const int arow = (lr < 32) ? lr : (96 + lr);      // quad-local -> tile row (q=0)
  const bf16_t* AsrcQ = Xb + (size_t)(bm * 256 + arow) * IN_F + sc;
  const bf16_t* Bsrc  = Wp + (size_t)(bn * 256 + lr) * IN_F + sc;

  // read-side per-thread offsets
  const int aRowB = (wr * 32 + r16) * 128;          // byte row offset within quad
  const int bRowB = (wc * 64 + r16) * 128;          // byte row offset in B tile
  const int cA0 = (kg * 16) ^ ((r16 & 7) << 4);     // swizzled col byte, k-half 0
  const int cA1 = cA0 ^ 64;                         // k-half 1

  f32x4 acc[8][4] = {};
  bf16x8 a[2][2], b[4][2];

  // prologue: tile 0 fully, tile 1 minus quad3 (staged at t=0 ph0).
  // Order mimics steady-state history so steady vmcnt tails stay exact.
  STAGE_AQ(0, 0, 0);
  STAGE_BH(0, 0, 0); STAGE_BH(0, 0, 1);
  STAGE_AQ(0, 0, 1); STAGE_AQ(0, 0, 2); STAGE_AQ(0, 0, 3);
  STAGE_BH(1, 1, 0); STAGE_AQ(1, 1, 0);
  STAGE_BH(1, 1, 1); STAGE_AQ(1, 1, 1);
  STAGE_AQ(1, 1, 2);
  WAIT_VM(10);                       // drain A0q0 + B0
  BARRIER();

  for (int t = 0; t < 62; ++t) {
    const int cur = t & 1;
    PH(0, cur, 1, { STAGE_AQ(t + 1, cur ^ 1, 3); },                      WAIT_VM(10));
    PH(1, cur, 0, { STAGE_BH(t + 2, cur, 0); STAGE_AQ(t + 2, cur, 0); }, WAIT_VM(12));
    PH(2, cur, 0, { STAGE_BH(t + 2, cur, 1); STAGE_AQ(t + 2, cur, 1); }, WAIT_VM(14));
    PH(3, cur, 0, { STAGE_AQ(t + 2, cur, 2); },                          WAIT_VM(10));
  }
  // t = 62 (cur=0): only A(63)q3 left to stage; drain progressively
  PH(0, 0, 1, { STAGE_AQ(63, 1, 3); }, WAIT_VM(10));
  PH(1, 0, 0, {},                      WAIT_VM(9));
  PH(2, 0, 0, {},                      WAIT_VM(8));
  PH(3, 0, 0, {},                      WAIT_VM(3));
  // t = 63 (cur=1)
  PH(0, 1, 1, {},                      WAIT_VM(2));
  PH(1, 1, 0, {},                      WAIT_VM(1));
  PH(2, 1, 0, {},                      WAIT_VM(0));
  PH(3, 1, 0, {},                      {});

  // epilogue: C/D layout col=lane&15, row=kg*4+reg (m89-verified)
#pragma unroll
  for (int n = 0; n < 4; ++n) {
    const int col = bn * 256 + wc * 64 + n * 16 + r16;
    const float bv = bias[col];
#pragma unroll
    for (int m = 0; m < 8; ++m) {
      const int row0 = bm * 256 + wr * 128 + m * 16 + kg * 4;
#pragma unroll
      for (int r = 0; r < 4; ++r)
        C[(size_t)(row0 + r) * OUT_F + col] = acc[m][n][r] + bv;
    }
  }
}

// ---------------------------------------------------------------------------
extern "C" void kernel_launch(void* const* d_in, const int* in_sizes, int n_in,
                              void* d_out, int out_size, void* d_ws, size_t ws_size,
                              hipStream_t stream) {
  const float* x  = (const float*)d_in[0];
  const int*   qw = (const int*)d_in[1];
  const float* wm = (const float*)d_in[2];
  const float* lA = (const float*)d_in[3];
  const float* lB = (const float*)d_in[4];
  const float* bs = (const float*)d_in[5];
  float* out = (float*)d_out;

  bf16_t* Wp = (bf16_t*)d_ws;                                        // 33.5 MB
  bf16_t* Xb = (bf16_t*)((char*)d_ws + (size_t)OUT_F * IN_F * 2);    // 67 MB

  dequant_lora_kernel<<<OUT_F * IN_F / 8 / 256, 256, 0, stream>>>(qw, wm, lA, lB, Wp);
  f32_to_bf16_kernel<<<M_ROWS * IN_F / 8 / 256, 256, 0, stream>>>(x, Xb);
  gemm_8phase_kernel<<<(M_ROWS / 256) * (OUT_F / 256), 512, 0, stream>>>(Xb, Wp, bs, out);
}